// Round 9
// baseline (3282.349 us; speedup 1.0000x reference)
//
#include <hip/hip_runtime.h>

constexpr int T = 12;
constexpr int NU = 10000;
constexpr int NT = 2500;
constexpr int FU = 64;
constexpr int FT = 32;
constexpr int H = 128;
constexpr int D = 256;
constexpr int E_TT = 50000;
constexpr int E_UT = 100000;
constexpr int E_TU = 100000;
constexpr float EPS = 1e-5f;

__device__ __forceinline__ void fma4(float4& a, const float4 x, const float4 w0,
                                     const float4 w1, const float4 w2, const float4 w3) {
  a.x += x.x * w0.x + x.y * w1.x + x.z * w2.x + x.w * w3.x;
  a.y += x.x * w0.y + x.y * w1.y + x.z * w2.y + x.w * w3.y;
  a.z += x.x * w0.z + x.y * w1.z + x.z * w2.z + x.w * w3.z;
  a.w += x.x * w0.w + x.y * w1.w + x.z * w2.w + x.w * w3.w;
}
__device__ __forceinline__ void add4(float4& a, const float4 v) {
  a.x += v.x; a.y += v.y; a.z += v.z; a.w += v.w;
}

// ---------------- BN statistics (partial sums, atomically combined) ----------------
__global__ __launch_bounds__(256) void bnsum_kernel(
    const float* __restrict__ x, int N, int F, float* __restrict__ sum,
    float* __restrict__ sq, int bpm) {
  int m = blockIdx.x / bpm, bc = blockIdx.x % bpm;
  int g = 256 / F;
  int c = threadIdx.x % F, rg = threadIdx.x / F;
  int rows = (N + bpm - 1) / bpm;
  int lo = bc * rows, hi = min(N, lo + rows);
  float s = 0.f, q = 0.f;
  for (int r = lo + rg; r < hi; r += g) {
    float v = x[((long)m * N + r) * F + c];
    s += v; q += v * v;
  }
  __shared__ float ssm[256], qsm[256];
  ssm[threadIdx.x] = s; qsm[threadIdx.x] = q;
  __syncthreads();
  if (rg == 0) {
    for (int i = 1; i < g; ++i) { s += ssm[i * F + c]; q += qsm[i * F + c]; }
    atomicAdd(&sum[m * F + c], s);
    atomicAdd(&sq[m * F + c], q);
  }
}

// ------- fused BN + projection: out[N,128] = bn(x) @ W + b  (32 rows x 128 cols/block)
template <int F>
__global__ __launch_bounds__(256) void proj_kernel(
    const float* __restrict__ x, const float* __restrict__ sum, const float* __restrict__ sq,
    const float* __restrict__ g, const float* __restrict__ b,
    const float* __restrict__ W, const float* __restrict__ pb,
    float* __restrict__ out, int N, int chunks) {
  constexpr int RPB = 32;
  constexpr int KG = F / 4;
  int m = blockIdx.x / chunks, chunk = blockIdx.x % chunks;
  int row0 = chunk * RPB;
  int nr = min(RPB, N - row0);
  int tid = threadIdx.x;
  int cg = tid & 31, rg = tid >> 5;
  int c4 = cg * 4, r0 = rg * 4;
  __shared__ __align__(16) float A[RPB][F];
  __shared__ __align__(16) float scv[F], shv[F];
  if (tid < F) {
    float mu = sum[m * F + tid] * (1.f / N);
    float var = sq[m * F + tid] * (1.f / N) - mu * mu;
    float inv = rsqrtf(var + EPS);
    float s = g[tid] * inv;
    scv[tid] = s; shv[tid] = b[tid] - mu * s;
  }
  __syncthreads();
  const float* xb = x + ((long)m * N + row0) * F;
  for (int i = tid; i < nr * KG; i += 256) {
    int r = i / KG, k4 = (i % KG) * 4;
    float4 xv = *(const float4*)&xb[r * F + k4];
    float4 s4 = *(const float4*)&scv[k4];
    float4 h4 = *(const float4*)&shv[k4];
    float4 a;
    a.x = xv.x * s4.x + h4.x; a.y = xv.y * s4.y + h4.y;
    a.z = xv.z * s4.z + h4.z; a.w = xv.w * s4.w + h4.w;
    *(float4*)&A[r][k4] = a;
  }
  __syncthreads();
  float4 acc[4] = {{0,0,0,0},{0,0,0,0},{0,0,0,0},{0,0,0,0}};
  for (int k = 0; k < F; k += 4) {
    float4 w0 = *(const float4*)&W[(k + 0) * H + c4];
    float4 w1 = *(const float4*)&W[(k + 1) * H + c4];
    float4 w2 = *(const float4*)&W[(k + 2) * H + c4];
    float4 w3 = *(const float4*)&W[(k + 3) * H + c4];
#pragma unroll
    for (int r = 0; r < 4; ++r)
      fma4(acc[r], *(const float4*)&A[r0 + r][k], w0, w1, w2, w3);
  }
  float4 bias = *(const float4*)&pb[c4];
  float* ob = out + ((long)m * N + row0) * H;
#pragma unroll
  for (int r = 0; r < 4; ++r)
    if (r0 + r < nr) {
      float4 o4;
      o4.x = acc[r].x + bias.x; o4.y = acc[r].y + bias.y;
      o4.z = acc[r].z + bias.z; o4.w = acc[r].w + bias.w;
      *(float4*)&ob[(r0 + r) * H + c4] = o4;
    }
}

// ---------------- CSR build ----------------
__global__ __launch_bounds__(256) void count_kernel(
    const int* __restrict__ dst, long mstride, int E, int* __restrict__ cnt, int N) {
  long idx = (long)blockIdx.x * 256 + threadIdx.x;
  if (idx >= (long)T * E) return;
  int m = (int)(idx / E), e = (int)(idx % E);
  int d = dst[m * mstride + e];
  atomicAdd(&cnt[m * N + d], 1);
}

__global__ __launch_bounds__(1024) void scan_kernel(
    int* __restrict__ iw, long cnt_tt, long off_tt, long cur_tt,
    long cnt_ut, long off_ut, long cur_ut,
    long cnt_tu, long off_tu, long cur_tu) {
  int b = blockIdx.x;
  int type = b / 12, m = b % 12;
  const int* cnt; int* off; int* cur; int N;
  if (type == 0) {
    cnt = iw + cnt_tt + (long)m * NT; off = iw + off_tt + (long)m * (NT + 1);
    cur = iw + cur_tt + (long)m * NT; N = NT;
  } else if (type == 1) {
    cnt = iw + cnt_ut + (long)m * NT; off = iw + off_ut + (long)m * (NT + 1);
    cur = iw + cur_ut + (long)m * NT; N = NT;
  } else {
    cnt = iw + cnt_tu + (long)m * NU; off = iw + off_tu + (long)m * (NU + 1);
    cur = iw + cur_tu + (long)m * NU; N = NU;
  }
  __shared__ int s[1024];
  int tid = threadIdx.x;
  int running = 0;
  for (int base = 0; base < N; base += 1024) {
    int i = base + tid;
    int v = (i < N) ? cnt[i] : 0;
    s[tid] = v;
    __syncthreads();
    for (int o = 1; o < 1024; o <<= 1) {
      int t = (tid >= o) ? s[tid - o] : 0;
      __syncthreads();
      s[tid] += t;
      __syncthreads();
    }
    if (i < N) { int e = running + s[tid] - v; off[i] = e; cur[i] = e; }
    int tot = s[1023];
    __syncthreads();
    running += tot;
  }
  if (tid == 0) off[N] = running;
}

__global__ __launch_bounds__(256) void fill_kernel(
    const int* __restrict__ src, long sstride, const int* __restrict__ dst, long dstride,
    int E, int* __restrict__ cur, int N, int* __restrict__ srcs) {
  long idx = (long)blockIdx.x * 256 + threadIdx.x;
  if (idx >= (long)T * E) return;
  int m = (int)(idx / E), e = (int)(idx % E);
  int d = dst[m * dstride + e];
  int sv = src[m * sstride + e];
  int pos = atomicAdd(&cur[m * N + d], 1);
  srcs[(long)m * E + pos] = sv;
}

// combined tag receive-weights: wrc[l] = Wr[l,0] + Wr[l,1]
__global__ __launch_bounds__(256) void combine_wr_kernel(
    const float* __restrict__ Wr, float* __restrict__ wrc) {
  int i = blockIdx.x * 256 + threadIdx.x;
  int l = i / (H * H), j = i % (H * H);
  wrc[i] = Wr[(long)(l * 3 + 0) * H * H + j] + Wr[(long)(l * 3 + 1) * H * H + j];
}

// ------- dst-centric mean aggregation, float4, gather unrolled x4 -------
__global__ __launch_bounds__(256) void agg_kernel(
    const int* __restrict__ off, const int* __restrict__ srcs,
    const float* __restrict__ xsrc, float* __restrict__ agg,
    int Ndst, int Nsrc, int E, int chunks) {
  int m = blockIdx.x / chunks, chunk = blockIdx.x % chunks;
  int slot = threadIdx.x >> 5;
  int c4 = (threadIdx.x & 31) * 4;
  int row = chunk * 8 + slot;
  if (row >= Ndst) return;
  const int* o = off + (long)m * (Ndst + 1);
  int o0 = o[row], o1 = o[row + 1];
  const int* sp = srcs + (long)m * E;
  const float* xb = xsrc + (long)m * Nsrc * H;
  float4 a0 = {0,0,0,0}, a1 = {0,0,0,0}, a2 = {0,0,0,0}, a3 = {0,0,0,0};
  int j = o0;
  for (; j + 3 < o1; j += 4) {
    int s0 = sp[j], s1 = sp[j + 1], s2 = sp[j + 2], s3 = sp[j + 3];
    add4(a0, *(const float4*)&xb[(long)s0 * H + c4]);
    add4(a1, *(const float4*)&xb[(long)s1 * H + c4]);
    add4(a2, *(const float4*)&xb[(long)s2 * H + c4]);
    add4(a3, *(const float4*)&xb[(long)s3 * H + c4]);
  }
  for (; j < o1; ++j) add4(a0, *(const float4*)&xb[(long)sp[j] * H + c4]);
  add4(a0, a1); add4(a2, a3); add4(a0, a2);
  float inv = 1.f / (float)max(o1 - o0, 1);
  a0.x *= inv; a0.y *= inv; a0.z *= inv; a0.w *= inv;
  *(float4*)&agg[((long)m * Ndst + row) * H + c4] = a0;
}

// ------- SAGE updates: W-in-registers / x-on-scalar-pipe structure -------
// Wave owns 16 rows x all 128 cols (lane = 2 cols). K in chunks of 32; the W
// chunk (32 x float2/lane = 64 VGPR) is register-resident and reused by all 16
// rows. The x-row address is wave-uniform, FORCED scalar via readfirstlane ->
// s_load on the SMEM pipe. Inner loop has zero LDS and zero per-row VMEM.
__global__ void update_user_kernel(
    float* __restrict__ xu, const float* __restrict__ aggtu,
    const float* __restrict__ Wl, const float* __restrict__ bl, const float* __restrict__ Wr,
    int layer, int chunks) {
  constexpr int G = 16;
  int m = blockIdx.x / chunks, chunk = blockIdx.x % chunks;
  int wave = threadIdx.x >> 6, lane = threadIdx.x & 63;
  int row0 = chunk * 64 + wave * G;
  int c2 = lane * 2;
  const float* wm0 = Wl + (long)(layer * 3 + 2) * H * H;
  const float* wm1 = Wr + (long)(layer * 3 + 2) * H * H;
  const float* xs0 = aggtu + (long)m * NU * H;
  const float* xs1 = xu + (long)m * NU * H;
  float2 acc[G];
#pragma unroll
  for (int r = 0; r < G; ++r) acc[r] = {0.f, 0.f};
#pragma unroll 1
  for (int mat = 0; mat < 2; ++mat) {
    const float* wm = (mat == 0) ? wm0 : wm1;
    const float* xs = (mat == 0) ? xs0 : xs1;
#pragma unroll 1
    for (int kc = 0; kc < H; kc += 32) {
      float2 wreg[32];
#pragma unroll
      for (int k = 0; k < 32; ++k)
        wreg[k] = *(const float2*)&wm[(kc + k) * H + c2];
#pragma unroll
      for (int r = 0; r < G; ++r) {
        int row = min(row0 + r, NU - 1);
        const float* xr = xs + (unsigned)__builtin_amdgcn_readfirstlane(row * H + kc);
#pragma unroll
        for (int k = 0; k < 32; k += 4) {
          float4 xv = *(const float4*)&xr[k];
          acc[r].x += xv.x * wreg[k].x + xv.y * wreg[k + 1].x
                    + xv.z * wreg[k + 2].x + xv.w * wreg[k + 3].x;
          acc[r].y += xv.x * wreg[k].y + xv.y * wreg[k + 1].y
                    + xv.z * wreg[k + 2].y + xv.w * wreg[k + 3].y;
        }
      }
    }
  }
  float2 bias = *(const float2*)&bl[(long)(layer * 3 + 2) * H + c2];
  float* ob = xu + (long)m * NU * H;
#pragma unroll
  for (int r = 0; r < G; ++r) {
    int row = row0 + r;
    if (row < NU) {
      float2 o2;
      o2.x = fmaxf(0.f, acc[r].x + bias.x);
      o2.y = fmaxf(0.f, acc[r].y + bias.y);
      *(float2*)&ob[(long)row * H + c2] = o2;
    }
  }
}

__global__ void update_tag_kernel(
    float* __restrict__ xt, const float* __restrict__ aggtt, const float* __restrict__ aggut,
    const float* __restrict__ Wl, const float* __restrict__ bl, const float* __restrict__ wrc,
    int layer, int chunks) {
  constexpr int G = 16;
  int m = blockIdx.x / chunks, chunk = blockIdx.x % chunks;
  int wave = threadIdx.x >> 6, lane = threadIdx.x & 63;
  int row0 = chunk * 64 + wave * G;
  int c2 = lane * 2;
  const float* wm0 = Wl + (long)(layer * 3 + 0) * H * H;
  const float* wm1 = wrc + (long)layer * H * H;
  const float* wm2 = Wl + (long)(layer * 3 + 1) * H * H;
  const float* xs0 = aggtt + (long)m * NT * H;
  const float* xs1 = xt + (long)m * NT * H;
  const float* xs2 = aggut + (long)m * NT * H;
  float2 acc[G];
#pragma unroll
  for (int r = 0; r < G; ++r) acc[r] = {0.f, 0.f};
#pragma unroll 1
  for (int mat = 0; mat < 3; ++mat) {
    const float* wm = (mat == 0) ? wm0 : (mat == 1) ? wm1 : wm2;
    const float* xs = (mat == 0) ? xs0 : (mat == 1) ? xs1 : xs2;
#pragma unroll 1
    for (int kc = 0; kc < H; kc += 32) {
      float2 wreg[32];
#pragma unroll
      for (int k = 0; k < 32; ++k)
        wreg[k] = *(const float2*)&wm[(kc + k) * H + c2];
#pragma unroll
      for (int r = 0; r < G; ++r) {
        int row = min(row0 + r, NT - 1);
        const float* xr = xs + (unsigned)__builtin_amdgcn_readfirstlane(row * H + kc);
#pragma unroll
        for (int k = 0; k < 32; k += 4) {
          float4 xv = *(const float4*)&xr[k];
          acc[r].x += xv.x * wreg[k].x + xv.y * wreg[k + 1].x
                    + xv.z * wreg[k + 2].x + xv.w * wreg[k + 3].x;
          acc[r].y += xv.x * wreg[k].y + xv.y * wreg[k + 1].y
                    + xv.z * wreg[k + 2].y + xv.w * wreg[k + 3].y;
        }
      }
    }
  }
  float2 b0 = *(const float2*)&bl[(long)(layer * 3 + 0) * H + c2];
  float2 b1 = *(const float2*)&bl[(long)(layer * 3 + 1) * H + c2];
  float* ob = xt + (long)m * NT * H;
#pragma unroll
  for (int r = 0; r < G; ++r) {
    int row = row0 + r;
    if (row < NT) {
      float2 o2;
      o2.x = fmaxf(0.f, 0.5f * (acc[r].x + b0.x + b1.x));
      o2.y = fmaxf(0.f, 0.5f * (acc[r].y + b0.y + b1.y));
      *(float2*)&ob[(long)row * H + c2] = o2;
    }
  }
}

// ---------------- mean pooling into emb (float4, LDS reduce, 4 atomics/thread) ------
__global__ __launch_bounds__(256) void pool_kernel(
    const float* __restrict__ x, int N, float* __restrict__ emb, int base, int bpm) {
  int m = blockIdx.x / bpm, bc = blockIdx.x % bpm;
  int cg = threadIdx.x & 31, rg = threadIdx.x >> 5;
  int c4 = cg * 4;
  int rows = (N + bpm - 1) / bpm;
  int lo = bc * rows, hi = min(N, lo + rows);
  float4 acc = {0,0,0,0};
  for (int r = lo + rg; r < hi; r += 8)
    add4(acc, *(const float4*)&x[((long)m * N + r) * H + c4]);
  __shared__ __align__(16) float4 sm[8][32];
  sm[rg][cg] = acc;
  __syncthreads();
  if (rg == 0) {
    float4 s = sm[0][cg];
#pragma unroll
    for (int i = 1; i < 8; ++i) add4(s, sm[i][cg]);
    float inv = 1.f / (float)N;
    atomicAdd(&emb[m * D + base + c4 + 0], s.x * inv);
    atomicAdd(&emb[m * D + base + c4 + 1], s.y * inv);
    atomicAdd(&emb[m * D + base + c4 + 2], s.z * inv);
    atomicAdd(&emb[m * D + base + c4 + 3], s.w * inv);
  }
}

// ================= transformer: multi-block pipeline =================
__device__ __forceinline__ void mm_slice(const float (&Xs)[12][256], const float* __restrict__ W,
                                         int ks, int tid, float* __restrict__ pOut) {
  int cg = tid & 63, rg = tid >> 6;
  int c4 = cg * 4;
  int s0 = rg * 3;
  float4 a0 = {0, 0, 0, 0}, a1 = {0, 0, 0, 0}, a2 = {0, 0, 0, 0};
  for (int k = ks * 64; k < ks * 64 + 64; k += 4) {
    float4 w0 = *(const float4*)&W[(k + 0) * 256 + c4];
    float4 w1 = *(const float4*)&W[(k + 1) * 256 + c4];
    float4 w2 = *(const float4*)&W[(k + 2) * 256 + c4];
    float4 w3 = *(const float4*)&W[(k + 3) * 256 + c4];
    fma4(a0, *(const float4*)&Xs[s0 + 0][k], w0, w1, w2, w3);
    fma4(a1, *(const float4*)&Xs[s0 + 1][k], w0, w1, w2, w3);
    fma4(a2, *(const float4*)&Xs[s0 + 2][k], w0, w1, w2, w3);
  }
  *(float4*)&pOut[(s0 + 0) * 256 + c4] = a0;
  *(float4*)&pOut[(s0 + 1) * 256 + c4] = a1;
  *(float4*)&pOut[(s0 + 2) * 256 + c4] = a2;
}

__device__ __forceinline__ void ln_rows(float (&Xs)[12][256], const float* __restrict__ g,
                                        const float* __restrict__ b, float (&rs)[4],
                                        float (&rq)[4], int tid) {
  for (int s = 0; s < 12; ++s) {
    float v = Xs[s][tid];
    float sm_ = v, sq_ = v * v;
    for (int o = 32; o > 0; o >>= 1) {
      sm_ += __shfl_down(sm_, o);
      sq_ += __shfl_down(sq_, o);
    }
    if ((tid & 63) == 0) { rs[tid >> 6] = sm_; rq[tid >> 6] = sq_; }
    __syncthreads();
    float mu = (rs[0] + rs[1] + rs[2] + rs[3]) * (1.f / 256);
    float var = (rq[0] + rq[1] + rq[2] + rq[3]) * (1.f / 256) - mu * mu;
    Xs[s][tid] = (v - mu) * rsqrtf(var + EPS) * g[tid] + b[tid];
    __syncthreads();
  }
}

__global__ __launch_bounds__(256) void trans_qkv(
    const float* __restrict__ xb, const float* __restrict__ pF2, const float* __restrict__ x1v,
    const float* __restrict__ b2, const float* __restrict__ ln2g, const float* __restrict__ ln2b,
    float* __restrict__ xb_out,
    const float* __restrict__ Wq, const float* __restrict__ Wk, const float* __restrict__ Wv,
    float* __restrict__ pQKV, int fuse) {
  __shared__ float Xs[12][256];
  __shared__ float rs[4], rq[4];
  int tid = threadIdx.x;
  int mat = blockIdx.x >> 2, ks = blockIdx.x & 3;
  if (fuse) {
    for (int s = 0; s < 12; ++s) {
      int i = s * 256 + tid;
      Xs[s][tid] = pF2[i] + pF2[3072 + i] + pF2[6144 + i] + pF2[9216 + i] + b2[tid] + x1v[i];
    }
    __syncthreads();
    ln_rows(Xs, ln2g, ln2b, rs, rq, tid);
    if (blockIdx.x == 0)
      for (int s = 0; s < 12; ++s) xb_out[s * 256 + tid] = Xs[s][tid];
  } else {
    for (int s = 0; s < 12; ++s) Xs[s][tid] = xb[s * 256 + tid];
    __syncthreads();
  }
  const float* W = (mat == 0) ? Wq : (mat == 1) ? Wk : Wv;
  mm_slice(Xs, W, ks, tid, pQKV + (mat * 4 + ks) * 3072);
}

__global__ __launch_bounds__(256) void trans_attn(
    const float* __restrict__ pQKV, const float* __restrict__ bq,
    const float* __restrict__ bk, const float* __restrict__ bv, float* __restrict__ O) {
  __shared__ float Qs[12][256], Ksh[12][256], Vs[12][256];
  __shared__ float Sc[4][12][12];
  int tid = threadIdx.x;
  for (int s = 0; s < 12; ++s) {
    int i = s * 256 + tid;
    const float* p = pQKV;
    Qs[s][tid] = p[i] + p[3072 + i] + p[6144 + i] + p[9216 + i] + bq[tid];
    p = pQKV + 12288;
    Ksh[s][tid] = p[i] + p[3072 + i] + p[6144 + i] + p[9216 + i] + bk[tid];
    p = pQKV + 24576;
    Vs[s][tid] = p[i] + p[3072 + i] + p[6144 + i] + p[9216 + i] + bv[tid];
  }
  __syncthreads();
  for (int idx = tid; idx < 576; idx += 256) {
    int h = idx / 144, rem = idx % 144, qi = rem / 12, ti = rem % 12;
    float acc = 0.f;
    for (int d = 0; d < 64; d += 4) {
      float4 qv = *(const float4*)&Qs[qi][h * 64 + d];
      float4 kv = *(const float4*)&Ksh[ti][h * 64 + d];
      acc += qv.x * kv.x + qv.y * kv.y + qv.z * kv.z + qv.w * kv.w;
    }
    Sc[h][qi][ti] = acc * 0.125f;
  }
  __syncthreads();
  if (tid < 48) {
    int h = tid / 12, qi = tid % 12;
    float mx = -1e30f;
    for (int t2 = 0; t2 < 12; ++t2) mx = fmaxf(mx, Sc[h][qi][t2]);
    float e[12], sum = 0.f;
    for (int t2 = 0; t2 < 12; ++t2) { e[t2] = __expf(Sc[h][qi][t2] - mx); sum += e[t2]; }
    float inv = 1.f / sum;
    for (int t2 = 0; t2 < 12; ++t2) Sc[h][qi][t2] = e[t2] * inv;
  }
  __syncthreads();
  int h = tid >> 6;
#pragma unroll
  for (int s = 0; s < 12; ++s) {
    float acc = 0.f;
#pragma unroll
    for (int t2 = 0; t2 < 12; ++t2) acc += Sc[h][s][t2] * Vs[t2][tid];
    O[s * 256 + tid] = acc;
  }
}

__global__ __launch_bounds__(256) void trans_mm(
    const float* __restrict__ In, const float* __restrict__ W, float* __restrict__ pOut) {
  __shared__ float Xs[12][256];
  int tid = threadIdx.x, ks = blockIdx.x;
  for (int s = 0; s < 12; ++s) Xs[s][tid] = In[s * 256 + tid];
  __syncthreads();
  mm_slice(Xs, W, ks, tid, pOut + ks * 3072);
}

__global__ __launch_bounds__(256) void trans_ffn1(
    const float* __restrict__ pP, const float* __restrict__ bo, const float* __restrict__ xb,
    const float* __restrict__ ln1g, const float* __restrict__ ln1b, float* __restrict__ x1_out,
    const float* __restrict__ W1, float* __restrict__ pF1) {
  __shared__ float Xs[12][256];
  __shared__ float rs[4], rq[4];
  int tid = threadIdx.x, ks = blockIdx.x;
  for (int s = 0; s < 12; ++s) {
    int i = s * 256 + tid;
    Xs[s][tid] = pP[i] + pP[3072 + i] + pP[6144 + i] + pP[9216 + i] + bo[tid] + xb[i];
  }
  __syncthreads();
  ln_rows(Xs, ln1g, ln1b, rs, rq, tid);
  if (ks == 0)
    for (int s = 0; s < 12; ++s) x1_out[s * 256 + tid] = Xs[s][tid];
  mm_slice(Xs, W1, ks, tid, pF1 + ks * 3072);
}

__global__ __launch_bounds__(256) void trans_ffn2(
    const float* __restrict__ pF1, const float* __restrict__ b1,
    const float* __restrict__ W2, float* __restrict__ pF2) {
  __shared__ float Xs[12][256];
  int tid = threadIdx.x, ks = blockIdx.x;
  for (int s = 0; s < 12; ++s) {
    int i = s * 256 + tid;
    Xs[s][tid] = fmaxf(0.f, pF1[i] + pF1[3072 + i] + pF1[6144 + i] + pF1[9216 + i] + b1[tid]);
  }
  __syncthreads();
  mm_slice(Xs, W2, ks, tid, pF2 + ks * 3072);
}

__global__ __launch_bounds__(256) void trans_head(
    const float* __restrict__ pF2, const float* __restrict__ b2, const float* __restrict__ x1v,
    const float* __restrict__ ln2g, const float* __restrict__ ln2b,
    const float* __restrict__ hW, const float* __restrict__ hb, float* __restrict__ out) {
  __shared__ float h[256];
  __shared__ float rs[4], rq[4];
  int tid = threadIdx.x;
  int i = 11 * 256 + tid;
  float v = pF2[i] + pF2[3072 + i] + pF2[6144 + i] + pF2[9216 + i] + b2[tid] + x1v[i];
  float sm_ = v, sq_ = v * v;
  for (int o = 32; o > 0; o >>= 1) { sm_ += __shfl_down(sm_, o); sq_ += __shfl_down(sq_, o); }
  if ((tid & 63) == 0) { rs[tid >> 6] = sm_; rq[tid >> 6] = sq_; }
  __syncthreads();
  float mu = (rs[0] + rs[1] + rs[2] + rs[3]) * (1.f / 256);
  float var = (rq[0] + rq[1] + rq[2] + rq[3]) * (1.f / 256) - mu * mu;
  h[tid] = (v - mu) * rsqrtf(var + EPS) * ln2g[tid] + ln2b[tid];
  __syncthreads();
  if (tid < 4) {
    float acc = hb[tid];
    for (int k = 0; k < 256; ++k) acc += h[k] * hW[k * 4 + tid];
    out[tid] = acc;
  }
}

extern "C" void kernel_launch(void* const* d_in, const int* in_sizes, int n_in,
                              void* d_out, int out_size, void* d_ws, size_t ws_size,
                              hipStream_t stream) {
  (void)in_sizes; (void)n_in; (void)out_size; (void)ws_size;
  const float* x_user = (const float*)d_in[0];
  const float* x_tag  = (const float*)d_in[1];
  const int* edge_tt  = (const int*)d_in[2];
  const int* e_us     = (const int*)d_in[3];
  const int* e_ud     = (const int*)d_in[4];
  const int* e_ts     = (const int*)d_in[5];
  const int* e_td     = (const int*)d_in[6];
  const float* bn_ug  = (const float*)d_in[7];
  const float* bn_ub  = (const float*)d_in[8];
  const float* bn_tg  = (const float*)d_in[9];
  const float* bn_tb  = (const float*)d_in[10];
  const float* pu_W   = (const float*)d_in[11];
  const float* pu_b   = (const float*)d_in[12];
  const float* pt_W   = (const float*)d_in[13];
  const float* pt_b   = (const float*)d_in[14];
  const float* cWl    = (const float*)d_in[15];
  const float* cbl    = (const float*)d_in[16];
  const float* cWr    = (const float*)d_in[17];
  const float* aWq    = (const float*)d_in[18];
  const float* abq    = (const float*)d_in[19];
  const float* aWk    = (const float*)d_in[20];
  const float* abk    = (const float*)d_in[21];
  const float* aWv    = (const float*)d_in[22];
  const float* abv    = (const float*)d_in[23];
  const float* aWo    = (const float*)d_in[24];
  const float* abo    = (const float*)d_in[25];
  const float* l1g    = (const float*)d_in[26];
  const float* l1b    = (const float*)d_in[27];
  const float* fW1    = (const float*)d_in[28];
  const float* fb1    = (const float*)d_in[29];
  const float* fW2    = (const float*)d_in[30];
  const float* fb2    = (const float*)d_in[31];
  const float* l2g    = (const float*)d_in[32];
  const float* l2b    = (const float*)d_in[33];
  const float* hW     = (const float*)d_in[34];
  const float* hb     = (const float*)d_in[35];

  float* ws = (float*)d_ws;
  int* iw = (int*)d_ws;
  size_t o = 0;
  auto alloc = [&](size_t n) { size_t r = o; o += n; return r; };
  size_t sum_u = alloc(T * FU), sq_u = alloc(T * FU);
  size_t sum_t = alloc(T * FT), sq_t = alloc(T * FT);
  size_t cnt_tt = alloc((size_t)T * NT), cnt_ut = alloc((size_t)T * NT), cnt_tu = alloc((size_t)T * NU);
  size_t emb = alloc(T * D);
  size_t zeroElems = o;
  size_t off_tt = alloc((size_t)T * (NT + 1)), off_ut = alloc((size_t)T * (NT + 1)), off_tu = alloc((size_t)T * (NU + 1));
  size_t cur_tt = alloc((size_t)T * NT), cur_ut = alloc((size_t)T * NT), cur_tu = alloc((size_t)T * NU);
  size_t srcs_tt = alloc((size_t)T * E_TT), srcs_ut = alloc((size_t)T * E_UT), srcs_tu = alloc((size_t)T * E_TU);
  size_t xu = alloc((size_t)T * NU * H), xt = alloc((size_t)T * NT * H);
  size_t agg_tt = alloc((size_t)T * NT * H), agg_ut = alloc((size_t)T * NT * H), agg_tu = alloc((size_t)T * NU * H);

  // cnt_* region is dead after scan_kernel: reuse for wrc (during conv loop)
  // and for transformer partial buffers (after conv). Total 129024 < 180000 ints.
  size_t wrc  = cnt_tt;            // 49152 floats (3*128*128), conv-loop lifetime
  size_t pQKV = cnt_tt + 49152;    // 36864 floats
  size_t pP   = cnt_tt + 86016;    // 12288 floats
  size_t pF1  = cnt_tt + 98304;    // 12288 floats
  size_t pF2  = cnt_tt + 110592;   // 12288 floats
  size_t Ob   = cnt_tt + 122880;   // 3072 floats
  size_t x1b  = cnt_tt + 125952;   // 3072 floats

  (void)hipMemsetAsync(d_ws, 0, zeroElems * sizeof(float), stream);

  // BN stats
  bnsum_kernel<<<dim3(T * 8), 256, 0, stream>>>(x_user, NU, FU, ws + sum_u, ws + sq_u, 8);
  bnsum_kernel<<<dim3(T * 4), 256, 0, stream>>>(x_tag, NT, FT, ws + sum_t, ws + sq_t, 4);
  // BN + projection
  int pch_u = (NU + 31) / 32, pch_t = (NT + 31) / 32;
  proj_kernel<FU><<<dim3(T * pch_u), 256, 0, stream>>>(
      x_user, ws + sum_u, ws + sq_u, bn_ug, bn_ub, pu_W, pu_b, ws + xu, NU, pch_u);
  proj_kernel<FT><<<dim3(T * pch_t), 256, 0, stream>>>(
      x_tag, ws + sum_t, ws + sq_t, bn_tg, bn_tb, pt_W, pt_b, ws + xt, NT, pch_t);
  // CSR build
  count_kernel<<<dim3((T * E_TT + 255) / 256), 256, 0, stream>>>(edge_tt + E_TT, 2L * E_TT, E_TT, iw + cnt_tt, NT);
  count_kernel<<<dim3((T * E_UT + 255) / 256), 256, 0, stream>>>(e_ud, E_UT, E_UT, iw + cnt_ut, NT);
  count_kernel<<<dim3((T * E_TU + 255) / 256), 256, 0, stream>>>(e_td, E_TU, E_TU, iw + cnt_tu, NU);
  scan_kernel<<<dim3(36), 1024, 0, stream>>>(iw, (long)cnt_tt, (long)off_tt, (long)cur_tt,
                                             (long)cnt_ut, (long)off_ut, (long)cur_ut,
                                             (long)cnt_tu, (long)off_tu, (long)cur_tu);
  // cnt dead from here; build combined tag weights into its slot
  combine_wr_kernel<<<dim3(192), 256, 0, stream>>>(cWr, ws + wrc);
  fill_kernel<<<dim3((T * E_TT + 255) / 256), 256, 0, stream>>>(edge_tt, 2L * E_TT, edge_tt + E_TT, 2L * E_TT, E_TT, iw + cur_tt, NT, iw + srcs_tt);
  fill_kernel<<<dim3((T * E_UT + 255) / 256), 256, 0, stream>>>(e_us, E_UT, e_ud, E_UT, E_UT, iw + cur_ut, NT, iw + srcs_ut);
  fill_kernel<<<dim3((T * E_TU + 255) / 256), 256, 0, stream>>>(e_ts, E_TU, e_td, E_TU, E_TU, iw + cur_tu, NU, iw + srcs_tu);
  // 3 hetero-SAGE layers
  int ach_t = (NT + 7) / 8, ach_u = (NU + 7) / 8;
  int uch_t = (NT + 63) / 64, uch_u = (NU + 63) / 64;
  for (int l = 0; l < 3; ++l) {
    agg_kernel<<<dim3(T * ach_t), 256, 0, stream>>>(iw + off_tt, iw + srcs_tt, ws + xt, ws + agg_tt, NT, NT, E_TT, ach_t);
    agg_kernel<<<dim3(T * ach_t), 256, 0, stream>>>(iw + off_ut, iw + srcs_ut, ws + xu, ws + agg_ut, NT, NU, E_UT, ach_t);
    agg_kernel<<<dim3(T * ach_u), 256, 0, stream>>>(iw + off_tu, iw + srcs_tu, ws + xt, ws + agg_tu, NU, NT, E_TU, ach_u);
    update_tag_kernel<<<dim3(T * uch_t), 256, 0, stream>>>(ws + xt, ws + agg_tt, ws + agg_ut, cWl, cbl, ws + wrc, l, uch_t);
    update_user_kernel<<<dim3(T * uch_u), 256, 0, stream>>>(ws + xu, ws + agg_tu, cWl, cbl, cWr, l, uch_u);
  }
  // mean pooling -> emb
  pool_kernel<<<dim3(T * 16), 256, 0, stream>>>(ws + xu, NU, ws + emb, 0, 16);
  pool_kernel<<<dim3(T * 8), 256, 0, stream>>>(ws + xt, NT, ws + emb, H, 8);
  // transformer pipeline
  long DD = (long)D * D;
  for (int l = 0; l < 3; ++l) {
    int fuse = (l > 0);
    int lp = fuse ? (l - 1) : 0;
    trans_qkv<<<dim3(12), 256, 0, stream>>>(
        ws + emb, ws + pF2, ws + x1b, fb2 + lp * D, l2g + lp * D, l2b + lp * D, ws + emb,
        aWq + l * DD, aWk + l * DD, aWv + l * DD, ws + pQKV, fuse);
    trans_attn<<<dim3(1), 256, 0, stream>>>(ws + pQKV, abq + l * D, abk + l * D, abv + l * D, ws + Ob);
    trans_mm<<<dim3(4), 256, 0, stream>>>(ws + Ob, aWo + l * DD, ws + pP);
    trans_ffn1<<<dim3(4), 256, 0, stream>>>(ws + pP, abo + l * D, ws + emb, l1g + l * D, l1b + l * D,
                                            ws + x1b, fW1 + l * DD, ws + pF1);
    trans_ffn2<<<dim3(4), 256, 0, stream>>>(ws + pF1, fb1 + l * D, fW2 + l * DD, ws + pF2);
  }
  trans_head<<<dim3(1), 256, 0, stream>>>(ws + pF2, fb2 + 2 * D, ws + x1b, l2g + 2 * D, l2b + 2 * D,
                                          hW, hb, (float*)d_out);
}

// Round 10
// 2370.474 us; speedup vs baseline: 1.3847x; 1.3847x over previous
//
#include <hip/hip_runtime.h>

constexpr int T = 12;
constexpr int NU = 10000;
constexpr int NT = 2500;
constexpr int FU = 64;
constexpr int FT = 32;
constexpr int H = 128;
constexpr int D = 256;
constexpr int E_TT = 50000;
constexpr int E_UT = 100000;
constexpr int E_TU = 100000;
constexpr float EPS = 1e-5f;

__device__ __forceinline__ void fma4(float4& a, const float4 x, const float4 w0,
                                     const float4 w1, const float4 w2, const float4 w3) {
  a.x += x.x * w0.x + x.y * w1.x + x.z * w2.x + x.w * w3.x;
  a.y += x.x * w0.y + x.y * w1.y + x.z * w2.y + x.w * w3.y;
  a.z += x.x * w0.z + x.y * w1.z + x.z * w2.z + x.w * w3.z;
  a.w += x.x * w0.w + x.y * w1.w + x.z * w2.w + x.w * w3.w;
}
__device__ __forceinline__ void add4(float4& a, const float4 v) {
  a.x += v.x; a.y += v.y; a.z += v.z; a.w += v.w;
}

// ---------------- BN statistics (partial sums, atomically combined) ----------------
__global__ __launch_bounds__(256) void bnsum_kernel(
    const float* __restrict__ x, int N, int F, float* __restrict__ sum,
    float* __restrict__ sq, int bpm) {
  int m = blockIdx.x / bpm, bc = blockIdx.x % bpm;
  int g = 256 / F;
  int c = threadIdx.x % F, rg = threadIdx.x / F;
  int rows = (N + bpm - 1) / bpm;
  int lo = bc * rows, hi = min(N, lo + rows);
  float s = 0.f, q = 0.f;
  for (int r = lo + rg; r < hi; r += g) {
    float v = x[((long)m * N + r) * F + c];
    s += v; q += v * v;
  }
  __shared__ float ssm[256], qsm[256];
  ssm[threadIdx.x] = s; qsm[threadIdx.x] = q;
  __syncthreads();
  if (rg == 0) {
    for (int i = 1; i < g; ++i) { s += ssm[i * F + c]; q += qsm[i * F + c]; }
    atomicAdd(&sum[m * F + c], s);
    atomicAdd(&sq[m * F + c], q);
  }
}

// ------- fused BN + projection: out[N,128] = bn(x) @ W + b  (32 rows x 128 cols/block)
template <int F>
__global__ __launch_bounds__(256) void proj_kernel(
    const float* __restrict__ x, const float* __restrict__ sum, const float* __restrict__ sq,
    const float* __restrict__ g, const float* __restrict__ b,
    const float* __restrict__ W, const float* __restrict__ pb,
    float* __restrict__ out, int N, int chunks) {
  constexpr int RPB = 32;
  constexpr int KG = F / 4;
  int m = blockIdx.x / chunks, chunk = blockIdx.x % chunks;
  int row0 = chunk * RPB;
  int nr = min(RPB, N - row0);
  int tid = threadIdx.x;
  int cg = tid & 31, rg = tid >> 5;
  int c4 = cg * 4, r0 = rg * 4;
  __shared__ __align__(16) float A[RPB][F];
  __shared__ __align__(16) float scv[F], shv[F];
  if (tid < F) {
    float mu = sum[m * F + tid] * (1.f / N);
    float var = sq[m * F + tid] * (1.f / N) - mu * mu;
    float inv = rsqrtf(var + EPS);
    float s = g[tid] * inv;
    scv[tid] = s; shv[tid] = b[tid] - mu * s;
  }
  __syncthreads();
  const float* xb = x + ((long)m * N + row0) * F;
  for (int i = tid; i < nr * KG; i += 256) {
    int r = i / KG, k4 = (i % KG) * 4;
    float4 xv = *(const float4*)&xb[r * F + k4];
    float4 s4 = *(const float4*)&scv[k4];
    float4 h4 = *(const float4*)&shv[k4];
    float4 a;
    a.x = xv.x * s4.x + h4.x; a.y = xv.y * s4.y + h4.y;
    a.z = xv.z * s4.z + h4.z; a.w = xv.w * s4.w + h4.w;
    *(float4*)&A[r][k4] = a;
  }
  __syncthreads();
  float4 acc[4] = {{0,0,0,0},{0,0,0,0},{0,0,0,0},{0,0,0,0}};
  for (int k = 0; k < F; k += 4) {
    float4 w0 = *(const float4*)&W[(k + 0) * H + c4];
    float4 w1 = *(const float4*)&W[(k + 1) * H + c4];
    float4 w2 = *(const float4*)&W[(k + 2) * H + c4];
    float4 w3 = *(const float4*)&W[(k + 3) * H + c4];
#pragma unroll
    for (int r = 0; r < 4; ++r)
      fma4(acc[r], *(const float4*)&A[r0 + r][k], w0, w1, w2, w3);
  }
  float4 bias = *(const float4*)&pb[c4];
  float* ob = out + ((long)m * N + row0) * H;
#pragma unroll
  for (int r = 0; r < 4; ++r)
    if (r0 + r < nr) {
      float4 o4;
      o4.x = acc[r].x + bias.x; o4.y = acc[r].y + bias.y;
      o4.z = acc[r].z + bias.z; o4.w = acc[r].w + bias.w;
      *(float4*)&ob[(r0 + r) * H + c4] = o4;
    }
}

// ---------------- CSR build ----------------
__global__ __launch_bounds__(256) void count_kernel(
    const int* __restrict__ dst, long mstride, int E, int* __restrict__ cnt, int N) {
  long idx = (long)blockIdx.x * 256 + threadIdx.x;
  if (idx >= (long)T * E) return;
  int m = (int)(idx / E), e = (int)(idx % E);
  int d = dst[m * mstride + e];
  atomicAdd(&cnt[m * N + d], 1);
}

__global__ __launch_bounds__(1024) void scan_kernel(
    int* __restrict__ iw, long cnt_tt, long off_tt, long cur_tt,
    long cnt_ut, long off_ut, long cur_ut,
    long cnt_tu, long off_tu, long cur_tu) {
  int b = blockIdx.x;
  int type = b / 12, m = b % 12;
  const int* cnt; int* off; int* cur; int N;
  if (type == 0) {
    cnt = iw + cnt_tt + (long)m * NT; off = iw + off_tt + (long)m * (NT + 1);
    cur = iw + cur_tt + (long)m * NT; N = NT;
  } else if (type == 1) {
    cnt = iw + cnt_ut + (long)m * NT; off = iw + off_ut + (long)m * (NT + 1);
    cur = iw + cur_ut + (long)m * NT; N = NT;
  } else {
    cnt = iw + cnt_tu + (long)m * NU; off = iw + off_tu + (long)m * (NU + 1);
    cur = iw + cur_tu + (long)m * NU; N = NU;
  }
  __shared__ int s[1024];
  int tid = threadIdx.x;
  int running = 0;
  for (int base = 0; base < N; base += 1024) {
    int i = base + tid;
    int v = (i < N) ? cnt[i] : 0;
    s[tid] = v;
    __syncthreads();
    for (int o = 1; o < 1024; o <<= 1) {
      int t = (tid >= o) ? s[tid - o] : 0;
      __syncthreads();
      s[tid] += t;
      __syncthreads();
    }
    if (i < N) { int e = running + s[tid] - v; off[i] = e; cur[i] = e; }
    int tot = s[1023];
    __syncthreads();
    running += tot;
  }
  if (tid == 0) off[N] = running;
}

__global__ __launch_bounds__(256) void fill_kernel(
    const int* __restrict__ src, long sstride, const int* __restrict__ dst, long dstride,
    int E, int* __restrict__ cur, int N, int* __restrict__ srcs) {
  long idx = (long)blockIdx.x * 256 + threadIdx.x;
  if (idx >= (long)T * E) return;
  int m = (int)(idx / E), e = (int)(idx % E);
  int d = dst[m * dstride + e];
  int sv = src[m * sstride + e];
  int pos = atomicAdd(&cur[m * N + d], 1);
  srcs[(long)m * E + pos] = sv;
}

// combined tag receive-weights: wrc[l] = Wr[l,0] + Wr[l,1]
__global__ __launch_bounds__(256) void combine_wr_kernel(
    const float* __restrict__ Wr, float* __restrict__ wrc) {
  int i = blockIdx.x * 256 + threadIdx.x;
  int l = i / (H * H), j = i % (H * H);
  wrc[i] = Wr[(long)(l * 3 + 0) * H * H + j] + Wr[(long)(l * 3 + 1) * H * H + j];
}

// ------- dst-centric mean aggregation, float4, gather unrolled x4 -------
__global__ __launch_bounds__(256) void agg_kernel(
    const int* __restrict__ off, const int* __restrict__ srcs,
    const float* __restrict__ xsrc, float* __restrict__ agg,
    int Ndst, int Nsrc, int E, int chunks) {
  int m = blockIdx.x / chunks, chunk = blockIdx.x % chunks;
  int slot = threadIdx.x >> 5;
  int c4 = (threadIdx.x & 31) * 4;
  int row = chunk * 8 + slot;
  if (row >= Ndst) return;
  const int* o = off + (long)m * (Ndst + 1);
  int o0 = o[row], o1 = o[row + 1];
  const int* sp = srcs + (long)m * E;
  const float* xb = xsrc + (long)m * Nsrc * H;
  float4 a0 = {0,0,0,0}, a1 = {0,0,0,0}, a2 = {0,0,0,0}, a3 = {0,0,0,0};
  int j = o0;
  for (; j + 3 < o1; j += 4) {
    int s0 = sp[j], s1 = sp[j + 1], s2 = sp[j + 2], s3 = sp[j + 3];
    add4(a0, *(const float4*)&xb[(long)s0 * H + c4]);
    add4(a1, *(const float4*)&xb[(long)s1 * H + c4]);
    add4(a2, *(const float4*)&xb[(long)s2 * H + c4]);
    add4(a3, *(const float4*)&xb[(long)s3 * H + c4]);
  }
  for (; j < o1; ++j) add4(a0, *(const float4*)&xb[(long)sp[j] * H + c4]);
  add4(a0, a1); add4(a2, a3); add4(a0, a2);
  float inv = 1.f / (float)max(o1 - o0, 1);
  a0.x *= inv; a0.y *= inv; a0.z *= inv; a0.w *= inv;
  *(float4*)&agg[((long)m * Ndst + row) * H + c4] = a0;
}

// ------- SAGE updates: REVERTED to the r1 structure (best measured: 205 us) -------
// 128 threads = 16 rows x 128 cols; thread = column c over 16 rows. x staged in
// LDS, read as wave-uniform BROADCASTS (free); W reads coalesced, amortized over
// 16 rows and L2-resident. tag keeps the wrc precombine (3 matrices, not 4).
__global__ __launch_bounds__(128) void update_tag_kernel(
    float* __restrict__ xt, const float* __restrict__ aggtt, const float* __restrict__ aggut,
    const float* __restrict__ Wl, const float* __restrict__ bl, const float* __restrict__ wrc,
    int layer, int chunks) {
  constexpr int RPB = 16;
  int m = blockIdx.x / chunks, chunk = blockIdx.x % chunks;
  int row0 = chunk * RPB;
  int nr = min(RPB, NT - row0);
  int c = threadIdx.x;
  __shared__ __align__(16) float sm0[RPB][H], sm1[RPB][H], sm2[RPB][H];
  const float* p0 = aggtt + ((long)m * NT + row0) * H;
  const float* p1 = xt + ((long)m * NT + row0) * H;
  const float* p2 = aggut + ((long)m * NT + row0) * H;
  for (int r = 0; r < nr; ++r) {
    sm0[r][c] = p0[r * H + c];
    sm1[r][c] = p1[r * H + c];
    sm2[r][c] = p2[r * H + c];
  }
  __syncthreads();
  const float* wl0 = Wl + (long)(layer * 3 + 0) * H * H;
  const float* wc = wrc + (long)layer * H * H;
  const float* wl1 = Wl + (long)(layer * 3 + 1) * H * H;
  float acc[RPB];
#pragma unroll
  for (int r = 0; r < RPB; ++r) acc[r] = 0.f;
  for (int k = 0; k < H; k += 4) {
    float a0[4], a1[4], a2[4];
#pragma unroll
    for (int u = 0; u < 4; ++u) {
      a0[u] = wl0[(k + u) * H + c];
      a1[u] = wc[(k + u) * H + c];
      a2[u] = wl1[(k + u) * H + c];
    }
#pragma unroll
    for (int r = 0; r < RPB; ++r) {
      float4 v0 = *(const float4*)&sm0[r][k];
      float4 v1 = *(const float4*)&sm1[r][k];
      float4 v2 = *(const float4*)&sm2[r][k];
      acc[r] += v0.x * a0[0] + v0.y * a0[1] + v0.z * a0[2] + v0.w * a0[3]
              + v1.x * a1[0] + v1.y * a1[1] + v1.z * a1[2] + v1.w * a1[3]
              + v2.x * a2[0] + v2.y * a2[1] + v2.z * a2[2] + v2.w * a2[3];
    }
  }
  float bias = bl[(layer * 3 + 0) * H + c] + bl[(layer * 3 + 1) * H + c];
  float* ob = xt + ((long)m * NT + row0) * H;
  for (int r = 0; r < nr; ++r) ob[r * H + c] = fmaxf(0.f, 0.5f * (acc[r] + bias));
}

__global__ __launch_bounds__(128) void update_user_kernel(
    float* __restrict__ xu, const float* __restrict__ aggtu,
    const float* __restrict__ Wl, const float* __restrict__ bl, const float* __restrict__ Wr,
    int layer, int chunks) {
  constexpr int RPB = 16;
  int m = blockIdx.x / chunks, chunk = blockIdx.x % chunks;
  int row0 = chunk * RPB;
  int nr = min(RPB, NU - row0);
  int c = threadIdx.x;
  __shared__ __align__(16) float sm0[RPB][H], sm1[RPB][H];
  const float* p0 = aggtu + ((long)m * NU + row0) * H;
  const float* p1 = xu + ((long)m * NU + row0) * H;
  for (int r = 0; r < nr; ++r) {
    sm0[r][c] = p0[r * H + c];
    sm1[r][c] = p1[r * H + c];
  }
  __syncthreads();
  const float* wl = Wl + (long)(layer * 3 + 2) * H * H;
  const float* wr = Wr + (long)(layer * 3 + 2) * H * H;
  float acc[RPB];
#pragma unroll
  for (int r = 0; r < RPB; ++r) acc[r] = 0.f;
  for (int k = 0; k < H; k += 4) {
    float a0[4], a1[4];
#pragma unroll
    for (int u = 0; u < 4; ++u) {
      a0[u] = wl[(k + u) * H + c];
      a1[u] = wr[(k + u) * H + c];
    }
#pragma unroll
    for (int r = 0; r < RPB; ++r) {
      float4 v0 = *(const float4*)&sm0[r][k];
      float4 v1 = *(const float4*)&sm1[r][k];
      acc[r] += v0.x * a0[0] + v0.y * a0[1] + v0.z * a0[2] + v0.w * a0[3]
              + v1.x * a1[0] + v1.y * a1[1] + v1.z * a1[2] + v1.w * a1[3];
    }
  }
  float bias = bl[(layer * 3 + 2) * H + c];
  float* ob = xu + ((long)m * NU + row0) * H;
  for (int r = 0; r < nr; ++r) ob[r * H + c] = fmaxf(0.f, acc[r] + bias);
}

// ---------------- mean pooling into emb (float4, LDS reduce, 4 atomics/thread) ------
__global__ __launch_bounds__(256) void pool_kernel(
    const float* __restrict__ x, int N, float* __restrict__ emb, int base, int bpm) {
  int m = blockIdx.x / bpm, bc = blockIdx.x % bpm;
  int cg = threadIdx.x & 31, rg = threadIdx.x >> 5;
  int c4 = cg * 4;
  int rows = (N + bpm - 1) / bpm;
  int lo = bc * rows, hi = min(N, lo + rows);
  float4 acc = {0,0,0,0};
  for (int r = lo + rg; r < hi; r += 8)
    add4(acc, *(const float4*)&x[((long)m * N + r) * H + c4]);
  __shared__ __align__(16) float4 sm[8][32];
  sm[rg][cg] = acc;
  __syncthreads();
  if (rg == 0) {
    float4 s = sm[0][cg];
#pragma unroll
    for (int i = 1; i < 8; ++i) add4(s, sm[i][cg]);
    float inv = 1.f / (float)N;
    atomicAdd(&emb[m * D + base + c4 + 0], s.x * inv);
    atomicAdd(&emb[m * D + base + c4 + 1], s.y * inv);
    atomicAdd(&emb[m * D + base + c4 + 2], s.z * inv);
    atomicAdd(&emb[m * D + base + c4 + 3], s.w * inv);
  }
}

// ================= transformer: multi-block pipeline =================
__device__ __forceinline__ void mm_slice(const float (&Xs)[12][256], const float* __restrict__ W,
                                         int ks, int tid, float* __restrict__ pOut) {
  int cg = tid & 63, rg = tid >> 6;
  int c4 = cg * 4;
  int s0 = rg * 3;
  float4 a0 = {0, 0, 0, 0}, a1 = {0, 0, 0, 0}, a2 = {0, 0, 0, 0};
  for (int k = ks * 64; k < ks * 64 + 64; k += 4) {
    float4 w0 = *(const float4*)&W[(k + 0) * 256 + c4];
    float4 w1 = *(const float4*)&W[(k + 1) * 256 + c4];
    float4 w2 = *(const float4*)&W[(k + 2) * 256 + c4];
    float4 w3 = *(const float4*)&W[(k + 3) * 256 + c4];
    fma4(a0, *(const float4*)&Xs[s0 + 0][k], w0, w1, w2, w3);
    fma4(a1, *(const float4*)&Xs[s0 + 1][k], w0, w1, w2, w3);
    fma4(a2, *(const float4*)&Xs[s0 + 2][k], w0, w1, w2, w3);
  }
  *(float4*)&pOut[(s0 + 0) * 256 + c4] = a0;
  *(float4*)&pOut[(s0 + 1) * 256 + c4] = a1;
  *(float4*)&pOut[(s0 + 2) * 256 + c4] = a2;
}

__device__ __forceinline__ void ln_rows(float (&Xs)[12][256], const float* __restrict__ g,
                                        const float* __restrict__ b, float (&rs)[4],
                                        float (&rq)[4], int tid) {
  for (int s = 0; s < 12; ++s) {
    float v = Xs[s][tid];
    float sm_ = v, sq_ = v * v;
    for (int o = 32; o > 0; o >>= 1) {
      sm_ += __shfl_down(sm_, o);
      sq_ += __shfl_down(sq_, o);
    }
    if ((tid & 63) == 0) { rs[tid >> 6] = sm_; rq[tid >> 6] = sq_; }
    __syncthreads();
    float mu = (rs[0] + rs[1] + rs[2] + rs[3]) * (1.f / 256);
    float var = (rq[0] + rq[1] + rq[2] + rq[3]) * (1.f / 256) - mu * mu;
    Xs[s][tid] = (v - mu) * rsqrtf(var + EPS) * g[tid] + b[tid];
    __syncthreads();
  }
}

__global__ __launch_bounds__(256) void trans_qkv(
    const float* __restrict__ xb, const float* __restrict__ pF2, const float* __restrict__ x1v,
    const float* __restrict__ b2, const float* __restrict__ ln2g, const float* __restrict__ ln2b,
    float* __restrict__ xb_out,
    const float* __restrict__ Wq, const float* __restrict__ Wk, const float* __restrict__ Wv,
    float* __restrict__ pQKV, int fuse) {
  __shared__ float Xs[12][256];
  __shared__ float rs[4], rq[4];
  int tid = threadIdx.x;
  int mat = blockIdx.x >> 2, ks = blockIdx.x & 3;
  if (fuse) {
    for (int s = 0; s < 12; ++s) {
      int i = s * 256 + tid;
      Xs[s][tid] = pF2[i] + pF2[3072 + i] + pF2[6144 + i] + pF2[9216 + i] + b2[tid] + x1v[i];
    }
    __syncthreads();
    ln_rows(Xs, ln2g, ln2b, rs, rq, tid);
    if (blockIdx.x == 0)
      for (int s = 0; s < 12; ++s) xb_out[s * 256 + tid] = Xs[s][tid];
  } else {
    for (int s = 0; s < 12; ++s) Xs[s][tid] = xb[s * 256 + tid];
    __syncthreads();
  }
  const float* W = (mat == 0) ? Wq : (mat == 1) ? Wk : Wv;
  mm_slice(Xs, W, ks, tid, pQKV + (mat * 4 + ks) * 3072);
}

__global__ __launch_bounds__(256) void trans_attn(
    const float* __restrict__ pQKV, const float* __restrict__ bq,
    const float* __restrict__ bk, const float* __restrict__ bv, float* __restrict__ O) {
  __shared__ float Qs[12][256], Ksh[12][256], Vs[12][256];
  __shared__ float Sc[4][12][12];
  int tid = threadIdx.x;
  for (int s = 0; s < 12; ++s) {
    int i = s * 256 + tid;
    const float* p = pQKV;
    Qs[s][tid] = p[i] + p[3072 + i] + p[6144 + i] + p[9216 + i] + bq[tid];
    p = pQKV + 12288;
    Ksh[s][tid] = p[i] + p[3072 + i] + p[6144 + i] + p[9216 + i] + bk[tid];
    p = pQKV + 24576;
    Vs[s][tid] = p[i] + p[3072 + i] + p[6144 + i] + p[9216 + i] + bv[tid];
  }
  __syncthreads();
  for (int idx = tid; idx < 576; idx += 256) {
    int h = idx / 144, rem = idx % 144, qi = rem / 12, ti = rem % 12;
    float acc = 0.f;
    for (int d = 0; d < 64; d += 4) {
      float4 qv = *(const float4*)&Qs[qi][h * 64 + d];
      float4 kv = *(const float4*)&Ksh[ti][h * 64 + d];
      acc += qv.x * kv.x + qv.y * kv.y + qv.z * kv.z + qv.w * kv.w;
    }
    Sc[h][qi][ti] = acc * 0.125f;
  }
  __syncthreads();
  if (tid < 48) {
    int h = tid / 12, qi = tid % 12;
    float mx = -1e30f;
    for (int t2 = 0; t2 < 12; ++t2) mx = fmaxf(mx, Sc[h][qi][t2]);
    float e[12], sum = 0.f;
    for (int t2 = 0; t2 < 12; ++t2) { e[t2] = __expf(Sc[h][qi][t2] - mx); sum += e[t2]; }
    float inv = 1.f / sum;
    for (int t2 = 0; t2 < 12; ++t2) Sc[h][qi][t2] = e[t2] * inv;
  }
  __syncthreads();
  int h = tid >> 6;
#pragma unroll
  for (int s = 0; s < 12; ++s) {
    float acc = 0.f;
#pragma unroll
    for (int t2 = 0; t2 < 12; ++t2) acc += Sc[h][s][t2] * Vs[t2][tid];
    O[s * 256 + tid] = acc;
  }
}

__global__ __launch_bounds__(256) void trans_mm(
    const float* __restrict__ In, const float* __restrict__ W, float* __restrict__ pOut) {
  __shared__ float Xs[12][256];
  int tid = threadIdx.x, ks = blockIdx.x;
  for (int s = 0; s < 12; ++s) Xs[s][tid] = In[s * 256 + tid];
  __syncthreads();
  mm_slice(Xs, W, ks, tid, pOut + ks * 3072);
}

__global__ __launch_bounds__(256) void trans_ffn1(
    const float* __restrict__ pP, const float* __restrict__ bo, const float* __restrict__ xb,
    const float* __restrict__ ln1g, const float* __restrict__ ln1b, float* __restrict__ x1_out,
    const float* __restrict__ W1, float* __restrict__ pF1) {
  __shared__ float Xs[12][256];
  __shared__ float rs[4], rq[4];
  int tid = threadIdx.x, ks = blockIdx.x;
  for (int s = 0; s < 12; ++s) {
    int i = s * 256 + tid;
    Xs[s][tid] = pP[i] + pP[3072 + i] + pP[6144 + i] + pP[9216 + i] + bo[tid] + xb[i];
  }
  __syncthreads();
  ln_rows(Xs, ln1g, ln1b, rs, rq, tid);
  if (ks == 0)
    for (int s = 0; s < 12; ++s) x1_out[s * 256 + tid] = Xs[s][tid];
  mm_slice(Xs, W1, ks, tid, pF1 + ks * 3072);
}

__global__ __launch_bounds__(256) void trans_ffn2(
    const float* __restrict__ pF1, const float* __restrict__ b1,
    const float* __restrict__ W2, float* __restrict__ pF2) {
  __shared__ float Xs[12][256];
  int tid = threadIdx.x, ks = blockIdx.x;
  for (int s = 0; s < 12; ++s) {
    int i = s * 256 + tid;
    Xs[s][tid] = fmaxf(0.f, pF1[i] + pF1[3072 + i] + pF1[6144 + i] + pF1[9216 + i] + b1[tid]);
  }
  __syncthreads();
  mm_slice(Xs, W2, ks, tid, pF2 + ks * 3072);
}

__global__ __launch_bounds__(256) void trans_head(
    const float* __restrict__ pF2, const float* __restrict__ b2, const float* __restrict__ x1v,
    const float* __restrict__ ln2g, const float* __restrict__ ln2b,
    const float* __restrict__ hW, const float* __restrict__ hb, float* __restrict__ out) {
  __shared__ float h[256];
  __shared__ float rs[4], rq[4];
  int tid = threadIdx.x;
  int i = 11 * 256 + tid;
  float v = pF2[i] + pF2[3072 + i] + pF2[6144 + i] + pF2[9216 + i] + b2[tid] + x1v[i];
  float sm_ = v, sq_ = v * v;
  for (int o = 32; o > 0; o >>= 1) { sm_ += __shfl_down(sm_, o); sq_ += __shfl_down(sq_, o); }
  if ((tid & 63) == 0) { rs[tid >> 6] = sm_; rq[tid >> 6] = sq_; }
  __syncthreads();
  float mu = (rs[0] + rs[1] + rs[2] + rs[3]) * (1.f / 256);
  float var = (rq[0] + rq[1] + rq[2] + rq[3]) * (1.f / 256) - mu * mu;
  h[tid] = (v - mu) * rsqrtf(var + EPS) * ln2g[tid] + ln2b[tid];
  __syncthreads();
  if (tid < 4) {
    float acc = hb[tid];
    for (int k = 0; k < 256; ++k) acc += h[k] * hW[k * 4 + tid];
    out[tid] = acc;
  }
}

extern "C" void kernel_launch(void* const* d_in, const int* in_sizes, int n_in,
                              void* d_out, int out_size, void* d_ws, size_t ws_size,
                              hipStream_t stream) {
  (void)in_sizes; (void)n_in; (void)out_size; (void)ws_size;
  const float* x_user = (const float*)d_in[0];
  const float* x_tag  = (const float*)d_in[1];
  const int* edge_tt  = (const int*)d_in[2];
  const int* e_us     = (const int*)d_in[3];
  const int* e_ud     = (const int*)d_in[4];
  const int* e_ts     = (const int*)d_in[5];
  const int* e_td     = (const int*)d_in[6];
  const float* bn_ug  = (const float*)d_in[7];
  const float* bn_ub  = (const float*)d_in[8];
  const float* bn_tg  = (const float*)d_in[9];
  const float* bn_tb  = (const float*)d_in[10];
  const float* pu_W   = (const float*)d_in[11];
  const float* pu_b   = (const float*)d_in[12];
  const float* pt_W   = (const float*)d_in[13];
  const float* pt_b   = (const float*)d_in[14];
  const float* cWl    = (const float*)d_in[15];
  const float* cbl    = (const float*)d_in[16];
  const float* cWr    = (const float*)d_in[17];
  const float* aWq    = (const float*)d_in[18];
  const float* abq    = (const float*)d_in[19];
  const float* aWk    = (const float*)d_in[20];
  const float* abk    = (const float*)d_in[21];
  const float* aWv    = (const float*)d_in[22];
  const float* abv    = (const float*)d_in[23];
  const float* aWo    = (const float*)d_in[24];
  const float* abo    = (const float*)d_in[25];
  const float* l1g    = (const float*)d_in[26];
  const float* l1b    = (const float*)d_in[27];
  const float* fW1    = (const float*)d_in[28];
  const float* fb1    = (const float*)d_in[29];
  const float* fW2    = (const float*)d_in[30];
  const float* fb2    = (const float*)d_in[31];
  const float* l2g    = (const float*)d_in[32];
  const float* l2b    = (const float*)d_in[33];
  const float* hW     = (const float*)d_in[34];
  const float* hb     = (const float*)d_in[35];

  float* ws = (float*)d_ws;
  int* iw = (int*)d_ws;
  size_t o = 0;
  auto alloc = [&](size_t n) { size_t r = o; o += n; return r; };
  size_t sum_u = alloc(T * FU), sq_u = alloc(T * FU);
  size_t sum_t = alloc(T * FT), sq_t = alloc(T * FT);
  size_t cnt_tt = alloc((size_t)T * NT), cnt_ut = alloc((size_t)T * NT), cnt_tu = alloc((size_t)T * NU);
  size_t emb = alloc(T * D);
  size_t zeroElems = o;
  size_t off_tt = alloc((size_t)T * (NT + 1)), off_ut = alloc((size_t)T * (NT + 1)), off_tu = alloc((size_t)T * (NU + 1));
  size_t cur_tt = alloc((size_t)T * NT), cur_ut = alloc((size_t)T * NT), cur_tu = alloc((size_t)T * NU);
  size_t srcs_tt = alloc((size_t)T * E_TT), srcs_ut = alloc((size_t)T * E_UT), srcs_tu = alloc((size_t)T * E_TU);
  size_t xu = alloc((size_t)T * NU * H), xt = alloc((size_t)T * NT * H);
  size_t agg_tt = alloc((size_t)T * NT * H), agg_ut = alloc((size_t)T * NT * H), agg_tu = alloc((size_t)T * NU * H);

  // cnt_* region is dead after scan_kernel: reuse for wrc (during conv loop)
  // and for transformer partial buffers (after conv). Total 129024 < 180000 ints.
  size_t wrc  = cnt_tt;            // 49152 floats (3*128*128), conv-loop lifetime
  size_t pQKV = cnt_tt + 49152;    // 36864 floats
  size_t pP   = cnt_tt + 86016;    // 12288 floats
  size_t pF1  = cnt_tt + 98304;    // 12288 floats
  size_t pF2  = cnt_tt + 110592;   // 12288 floats
  size_t Ob   = cnt_tt + 122880;   // 3072 floats
  size_t x1b  = cnt_tt + 125952;   // 3072 floats

  (void)hipMemsetAsync(d_ws, 0, zeroElems * sizeof(float), stream);

  // BN stats
  bnsum_kernel<<<dim3(T * 8), 256, 0, stream>>>(x_user, NU, FU, ws + sum_u, ws + sq_u, 8);
  bnsum_kernel<<<dim3(T * 4), 256, 0, stream>>>(x_tag, NT, FT, ws + sum_t, ws + sq_t, 4);
  // BN + projection
  int pch_u = (NU + 31) / 32, pch_t = (NT + 31) / 32;
  proj_kernel<FU><<<dim3(T * pch_u), 256, 0, stream>>>(
      x_user, ws + sum_u, ws + sq_u, bn_ug, bn_ub, pu_W, pu_b, ws + xu, NU, pch_u);
  proj_kernel<FT><<<dim3(T * pch_t), 256, 0, stream>>>(
      x_tag, ws + sum_t, ws + sq_t, bn_tg, bn_tb, pt_W, pt_b, ws + xt, NT, pch_t);
  // CSR build
  count_kernel<<<dim3((T * E_TT + 255) / 256), 256, 0, stream>>>(edge_tt + E_TT, 2L * E_TT, E_TT, iw + cnt_tt, NT);
  count_kernel<<<dim3((T * E_UT + 255) / 256), 256, 0, stream>>>(e_ud, E_UT, E_UT, iw + cnt_ut, NT);
  count_kernel<<<dim3((T * E_TU + 255) / 256), 256, 0, stream>>>(e_td, E_TU, E_TU, iw + cnt_tu, NU);
  scan_kernel<<<dim3(36), 1024, 0, stream>>>(iw, (long)cnt_tt, (long)off_tt, (long)cur_tt,
                                             (long)cnt_ut, (long)off_ut, (long)cur_ut,
                                             (long)cnt_tu, (long)off_tu, (long)cur_tu);
  // cnt dead from here; build combined tag weights into its slot
  combine_wr_kernel<<<dim3(192), 256, 0, stream>>>(cWr, ws + wrc);
  fill_kernel<<<dim3((T * E_TT + 255) / 256), 256, 0, stream>>>(edge_tt, 2L * E_TT, edge_tt + E_TT, 2L * E_TT, E_TT, iw + cur_tt, NT, iw + srcs_tt);
  fill_kernel<<<dim3((T * E_UT + 255) / 256), 256, 0, stream>>>(e_us, E_UT, e_ud, E_UT, E_UT, iw + cur_ut, NT, iw + srcs_ut);
  fill_kernel<<<dim3((T * E_TU + 255) / 256), 256, 0, stream>>>(e_ts, E_TU, e_td, E_TU, E_TU, iw + cur_tu, NU, iw + srcs_tu);
  // 3 hetero-SAGE layers
  int ach_t = (NT + 7) / 8, ach_u = (NU + 7) / 8;
  int uch_t = (NT + 15) / 16, uch_u = (NU + 15) / 16;
  for (int l = 0; l < 3; ++l) {
    agg_kernel<<<dim3(T * ach_t), 256, 0, stream>>>(iw + off_tt, iw + srcs_tt, ws + xt, ws + agg_tt, NT, NT, E_TT, ach_t);
    agg_kernel<<<dim3(T * ach_t), 256, 0, stream>>>(iw + off_ut, iw + srcs_ut, ws + xu, ws + agg_ut, NT, NU, E_UT, ach_t);
    agg_kernel<<<dim3(T * ach_u), 256, 0, stream>>>(iw + off_tu, iw + srcs_tu, ws + xt, ws + agg_tu, NU, NT, E_TU, ach_u);
    update_tag_kernel<<<dim3(T * uch_t), 128, 0, stream>>>(ws + xt, ws + agg_tt, ws + agg_ut, cWl, cbl, ws + wrc, l, uch_t);
    update_user_kernel<<<dim3(T * uch_u), 128, 0, stream>>>(ws + xu, ws + agg_tu, cWl, cbl, cWr, l, uch_u);
  }
  // mean pooling -> emb
  pool_kernel<<<dim3(T * 16), 256, 0, stream>>>(ws + xu, NU, ws + emb, 0, 16);
  pool_kernel<<<dim3(T * 8), 256, 0, stream>>>(ws + xt, NT, ws + emb, H, 8);
  // transformer pipeline
  long DD = (long)D * D;
  for (int l = 0; l < 3; ++l) {
    int fuse = (l > 0);
    int lp = fuse ? (l - 1) : 0;
    trans_qkv<<<dim3(12), 256, 0, stream>>>(
        ws + emb, ws + pF2, ws + x1b, fb2 + lp * D, l2g + lp * D, l2b + lp * D, ws + emb,
        aWq + l * DD, aWk + l * DD, aWv + l * DD, ws + pQKV, fuse);
    trans_attn<<<dim3(1), 256, 0, stream>>>(ws + pQKV, abq + l * D, abk + l * D, abv + l * D, ws + Ob);
    trans_mm<<<dim3(4), 256, 0, stream>>>(ws + Ob, aWo + l * DD, ws + pP);
    trans_ffn1<<<dim3(4), 256, 0, stream>>>(ws + pP, abo + l * D, ws + emb, l1g + l * D, l1b + l * D,
                                            ws + x1b, fW1 + l * DD, ws + pF1);
    trans_ffn2<<<dim3(4), 256, 0, stream>>>(ws + pF1, fb1 + l * D, fW2 + l * DD, ws + pF2);
  }
  trans_head<<<dim3(1), 256, 0, stream>>>(ws + pF2, fb2 + 2 * D, ws + x1b, l2g + 2 * D, l2b + 2 * D,
                                          hW, hb, (float*)d_out);
}